// Round 2
// baseline (240.225 us; speedup 1.0000x reference)
//
#include <hip/hip_runtime.h>

// LIF scan, MLP-optimized: all 8 timestep loads are address-independent of the
// recurrence, so hoist them (8 outstanding global_load_dwordx4 per wave) before
// walking the sequential mem/spike chain. Prev version interleaved load->use
// per t (VGPR=28 proves it) and serialized on ~900-cyc HBM latency -> 2.3 TB/s.

#define DECAY  0.25f
#define THRESH 0.5f

__global__ __launch_bounds__(256) void lif_scan_kernel(
    const float4* __restrict__ x, float4* __restrict__ out, int n4) {
    const int i = blockIdx.x * blockDim.x + threadIdx.x;
    if (i >= n4) return;

    // Hoisted loads: 8 independent addresses -> 8 loads in flight per wave.
    float4 xv[8];
#pragma unroll
    for (int t = 0; t < 8; ++t) {
        xv[t] = x[(size_t)t * (size_t)n4 + (size_t)i];
    }

    float4 mem   = make_float4(0.f, 0.f, 0.f, 0.f);
    float4 spike = make_float4(0.f, 0.f, 0.f, 0.f);

#pragma unroll
    for (int t = 0; t < 8; ++t) {
        mem.x = mem.x * (DECAY * (1.f - spike.x)) + xv[t].x;
        mem.y = mem.y * (DECAY * (1.f - spike.y)) + xv[t].y;
        mem.z = mem.z * (DECAY * (1.f - spike.z)) + xv[t].z;
        mem.w = mem.w * (DECAY * (1.f - spike.w)) + xv[t].w;
        spike.x = (mem.x >= THRESH) ? 1.f : 0.f;
        spike.y = (mem.y >= THRESH) ? 1.f : 0.f;
        spike.z = (mem.z >= THRESH) ? 1.f : 0.f;
        spike.w = (mem.w >= THRESH) ? 1.f : 0.f;
        out[(size_t)t * (size_t)n4 + (size_t)i] = spike;  // store needs no wait
    }
}

extern "C" void kernel_launch(void* const* d_in, const int* in_sizes, int n_in,
                              void* d_out, int out_size, void* d_ws, size_t ws_size,
                              hipStream_t stream) {
    const float* x = (const float*)d_in[0];
    float* out = (float*)d_out;

    const int total = in_sizes[0];        // 8 * 32 * 128 * 32 * 32 = 33,554,432
    const int T = 8;
    const int n = total / T;              // 4,194,304 sites per timestep
    const int n4 = n / 4;                 // 1,048,576 float4 groups

    const int block = 256;
    const int grid = (n4 + block - 1) / block;  // 4096 blocks

    lif_scan_kernel<<<grid, block, 0, stream>>>(
        (const float4*)x, (float4*)out, n4);
}

// Round 3
// 236.715 us; speedup vs baseline: 1.0148x; 1.0148x over previous
//
#include <hip/hip_runtime.h>

// LIF scan over T=8. Round-2 post-mortem: compiler SANK the hoisted loads
// (VGPR stayed 28 — 8 live float4 need >=32), re-serializing each wave on one
// HBM round trip per t (~2.2 TB/s). Fix: hoist all 8 loads and pin them with
// __builtin_amdgcn_sched_barrier(0) so no load can sink below it. All loads
// are then older than every store -> the recurrence's vmcnt waits never block
// on store drain, and each wave keeps 8 KB in flight (8x MLP).

#define DECAY  0.25f
#define THRESH 0.5f

__global__ __launch_bounds__(256) void lif_scan_kernel(
    const float4* __restrict__ x, float4* __restrict__ out, int n4) {
    const int i = blockIdx.x * blockDim.x + threadIdx.x;
    if (i >= n4) return;

    const size_t base = (size_t)i;
    const size_t stride = (size_t)n4;

    // Issue all 8 loads back-to-back: 8 outstanding global_load_dwordx4/wave.
    float4 x0 = x[base + 0 * stride];
    float4 x1 = x[base + 1 * stride];
    float4 x2 = x[base + 2 * stride];
    float4 x3 = x[base + 3 * stride];
    float4 x4 = x[base + 4 * stride];
    float4 x5 = x[base + 5 * stride];
    float4 x6 = x[base + 6 * stride];
    float4 x7 = x[base + 7 * stride];
    // Hard fence: nothing moves across this — loads cannot be sunk.
    __builtin_amdgcn_sched_barrier(0);

    float4 mem   = make_float4(0.f, 0.f, 0.f, 0.f);
    float4 spike = make_float4(0.f, 0.f, 0.f, 0.f);

    float4 xv[8] = {x0, x1, x2, x3, x4, x5, x6, x7};
#pragma unroll
    for (int t = 0; t < 8; ++t) {
        mem.x = mem.x * (DECAY * (1.f - spike.x)) + xv[t].x;
        mem.y = mem.y * (DECAY * (1.f - spike.y)) + xv[t].y;
        mem.z = mem.z * (DECAY * (1.f - spike.z)) + xv[t].z;
        mem.w = mem.w * (DECAY * (1.f - spike.w)) + xv[t].w;
        spike.x = (mem.x >= THRESH) ? 1.f : 0.f;
        spike.y = (mem.y >= THRESH) ? 1.f : 0.f;
        spike.z = (mem.z >= THRESH) ? 1.f : 0.f;
        spike.w = (mem.w >= THRESH) ? 1.f : 0.f;
        out[base + (size_t)t * stride] = spike;
    }
}

extern "C" void kernel_launch(void* const* d_in, const int* in_sizes, int n_in,
                              void* d_out, int out_size, void* d_ws, size_t ws_size,
                              hipStream_t stream) {
    const float* x = (const float*)d_in[0];
    float* out = (float*)d_out;

    const int total = in_sizes[0];        // 8 * 32 * 128 * 32 * 32 = 33,554,432
    const int T = 8;
    const int n = total / T;              // 4,194,304 sites per timestep
    const int n4 = n / 4;                 // 1,048,576 float4 groups

    const int block = 256;
    const int grid = (n4 + block - 1) / block;  // 4096 blocks

    lif_scan_kernel<<<grid, block, 0, stream>>>(
        (const float4*)x, (float4*)out, n4);
}